// Round 3
// baseline (311.711 us; speedup 1.0000x reference)
//
#include <hip/hip_runtime.h>
#include <hip/hip_bf16.h>
#include <stdint.h>

#define NTOK 4096
#define DIN  2048
#define DOUT 2048
#define RANK 16
#define NLORA 32

typedef __attribute__((ext_vector_type(4))) float f32x4;
typedef __attribute__((ext_vector_type(8))) short bf16x8;
typedef __attribute__((ext_vector_type(8))) unsigned short u16x8;

typedef const __attribute__((address_space(1))) void* gas_ptr;
typedef __attribute__((address_space(3))) void* las_ptr;

__device__ __forceinline__ unsigned short f32_to_bf16_rne(float f) {
    union { float f; unsigned int u; } v; v.f = f;
    unsigned int u = v.u;
    unsigned int r = u + 0x7fffu + ((u >> 16) & 1u);
    return (unsigned short)(r >> 16);
}
__device__ __forceinline__ float bf16_bits_to_f32(unsigned short h) {
    union { unsigned int u; float f; } v; v.u = ((unsigned int)h) << 16;
    return v.f;
}

// ---------------------------------------------------------------------------
// K1: W split (blocks [0,2048)) + x split ([2048,6144)) + per-adapter token
// lists via wave ballot ([6144,6176)). No atomics; lists are deterministic.
// ---------------------------------------------------------------------------
__global__ __launch_bounds__(256)
void prep_kernel(const float* __restrict__ x, const int* __restrict__ ids,
                 const float* __restrict__ W,
                 unsigned short* __restrict__ x_hi, unsigned short* __restrict__ x_lo,
                 unsigned short* __restrict__ w_hi, unsigned short* __restrict__ w_lo,
                 int* __restrict__ list, int* __restrict__ counts) {
    const int bid = blockIdx.x;
    if (bid < 6144) {
        const float* src; unsigned short *dh, *dl;
        size_t i;
        if (bid < 2048) { src = W; dh = w_hi; dl = w_lo; i = ((size_t)bid * 256 + threadIdx.x) * 8; }
        else            { src = x; dh = x_hi; dl = x_lo; i = ((size_t)(bid - 2048) * 256 + threadIdx.x) * 8; }
        f32x4 a = *(const f32x4*)(src + i);
        f32x4 b = *(const f32x4*)(src + i + 4);
        float f[8] = {a.x, a.y, a.z, a.w, b.x, b.y, b.z, b.w};
        u16x8 h, l;
#pragma unroll
        for (int j = 0; j < 8; j++) {
            unsigned short hb = f32_to_bf16_rne(f[j]);
            h[j] = hb;
            l[j] = f32_to_bf16_rne(f[j] - bf16_bits_to_f32(hb));
        }
        *(u16x8*)(dh + i) = h;
        *(u16x8*)(dl + i) = l;
        return;
    }
    // ---- token-list building for adapter a ----
    const int a = bid - 6144;
    const int wv = threadIdx.x >> 6;
    const int lane = threadIdx.x & 63;
    __shared__ int wcnt[4];
    int c = 0;
    for (int t0 = wv * 1024; t0 < wv * 1024 + 1024; t0 += 64)
        c += __popcll(__ballot(ids[t0 + lane] == a));
    if (lane == 0) wcnt[wv] = c;
    __syncthreads();
    int off = 0;
    for (int w = 0; w < wv; w++) off += wcnt[w];
    if (threadIdx.x == 0) counts[a] = wcnt[0] + wcnt[1] + wcnt[2] + wcnt[3];
    for (int t0 = wv * 1024; t0 < wv * 1024 + 1024; t0 += 64) {
        const int t = t0 + lane;
        const bool m = (ids[t] == a);
        unsigned long long bal = __ballot(m);
        if (m) {
            int pos = off + __popcll(bal & ((1ULL << lane) - 1));
            list[a * NTOK + pos] = t;
        }
        off += __popcll(bal);
    }
}

// ---------------------------------------------------------------------------
// K2: grouped LoRA-A. Block (a, seg): lora_A[a] staged in 128 KB LDS; waves
// process token positions p = seg + 8*jj. Conflict-free LDS reads (consecutive
// lanes -> consecutive chunks). ares[t][r] = scal * dot(x[t], A[r]).
// ---------------------------------------------------------------------------
__global__ __launch_bounds__(256)
void lora_a_grouped(const float* __restrict__ x, const float* __restrict__ lA,
                    const float* __restrict__ scal, const int* __restrict__ list,
                    const int* __restrict__ counts, float* __restrict__ ares) {
    extern __shared__ float As_f[];           // [16][2048] f32 = 131072 B
    const int a = blockIdx.x, seg = blockIdx.y;
    for (int i = threadIdx.x; i < RANK * DIN; i += 256)
        As_f[i] = lA[(size_t)a * RANK * DIN + i];
    __syncthreads();
    const int wv = threadIdx.x >> 6, lane = threadIdx.x & 63;
    const int cnt = counts[a];
    const float s = scal[a];
    for (int jj = wv; seg + 8 * jj < cnt; jj += 4) {
        const int t = list[a * NTOK + seg + 8 * jj];
        const float* xr = x + (size_t)t * DIN;
        float accv[RANK];
#pragma unroll
        for (int r = 0; r < RANK; r++) accv[r] = 0.f;
        for (int cp = 0; cp < DIN; cp += 256) {
            const f32x4 xv = *(const f32x4*)(xr + cp + lane * 4);
#pragma unroll
            for (int r = 0; r < RANK; r++) {
                const f32x4 av = *(const f32x4*)(As_f + r * DIN + cp + lane * 4);
                accv[r] += xv.x * av.x + xv.y * av.y + xv.z * av.z + xv.w * av.w;
            }
        }
        float myv = 0.f;
#pragma unroll
        for (int r = 0; r < RANK; r++) {
            float v = accv[r];
#pragma unroll
            for (int off = 32; off > 0; off >>= 1) v += __shfl_xor(v, off);
            if (lane == r) myv = v;
        }
        if (lane < RANK) ares[(size_t)t * RANK + lane] = myv * s;
    }
}

// ---------------------------------------------------------------------------
// K3: grouped LoRA-B + bias. Block (a, seg): lora_B[a] staged TRANSPOSED in
// LDS as [r][o] with row stride 2052 (2-way max bank aliasing on write,
// conflict-free b128 reads). Bres[t][o] = bias[o] + sum_r ares[t][r]*B[o][r].
// ---------------------------------------------------------------------------
#define BSTR 2052
__global__ __launch_bounds__(256)
void lora_b_grouped(const float* __restrict__ lB, const float* __restrict__ bias,
                    const float* __restrict__ ares, const int* __restrict__ list,
                    const int* __restrict__ counts, float* __restrict__ Bres) {
    extern __shared__ float Bs_f[];           // [16][2052] f32 = 131328 B
    const int a = blockIdx.x, seg = blockIdx.y;
    for (int i = threadIdx.x; i < DOUT * RANK; i += 256) {
        const int r = i & 15, o = i >> 4;
        Bs_f[r * BSTR + o] = lB[(size_t)a * DOUT * RANK + i];
    }
    const int wv = threadIdx.x >> 6, lane = threadIdx.x & 63;
    f32x4 bias4[8];
#pragma unroll
    for (int cc = 0; cc < 8; cc++) bias4[cc] = *(const f32x4*)(bias + cc * 256 + lane * 4);
    __syncthreads();
    const int cnt = counts[a];
    for (int jj = wv; seg + 8 * jj < cnt; jj += 4) {
        const int t = list[a * NTOK + seg + 8 * jj];
        const float* ar = ares + (size_t)t * RANK;
        f32x4 a0 = *(const f32x4*)(ar);
        f32x4 a1 = *(const f32x4*)(ar + 4);
        f32x4 a2 = *(const f32x4*)(ar + 8);
        f32x4 a3 = *(const f32x4*)(ar + 12);
        const float sv[16] = {a0.x, a0.y, a0.z, a0.w, a1.x, a1.y, a1.z, a1.w,
                              a2.x, a2.y, a2.z, a2.w, a3.x, a3.y, a3.z, a3.w};
        f32x4 acc4[8];
#pragma unroll
        for (int cc = 0; cc < 8; cc++) acc4[cc] = bias4[cc];
#pragma unroll
        for (int r = 0; r < RANK; r++) {
            const float s = sv[r];
#pragma unroll
            for (int cc = 0; cc < 8; cc++) {
                const f32x4 bv = *(const f32x4*)(Bs_f + r * BSTR + cc * 256 + lane * 4);
                acc4[cc] += bv * s;
            }
        }
#pragma unroll
        for (int cc = 0; cc < 8; cc++)
            *(f32x4*)(Bres + (size_t)t * DOUT + cc * 256 + lane * 4) = acc4[cc];
    }
}

// ---------------------------------------------------------------------------
// K4: main GEMM. 256x128 tile, 8 waves (4x2 of 64x64), BK=32, LDS double-
// buffered (96 KB), 2-phase pipeline (prefetch next K-tile before compute,
// one barrier per K-step). Swizzled LDS (round-2-verified, conflicts=0).
// XCD-chunked block swizzle: each XCD owns 2 M-panels -> x-tiles L2-resident.
// Epilogue: out = acc + Bres (coalesced), no gathers.
// ---------------------------------------------------------------------------
#define BM 256
#define BN 128
#define BK 32
// LDS ushort offsets: As buf0 0, buf1 16384; Bs buf0 32768, buf1 40960

__global__ __launch_bounds__(512, 2)
void gemm_lora_kernel(const unsigned short* __restrict__ Ah,
                      const unsigned short* __restrict__ Al,
                      const unsigned short* __restrict__ Wh,
                      const unsigned short* __restrict__ Wl,
                      const float* __restrict__ Bres,
                      float* __restrict__ out) {
    extern __shared__ unsigned short sm[];
    unsigned short* As = sm;            // 2 x 16384
    unsigned short* Bs = sm + 32768;    // 2 x 8192

    const int tid = threadIdx.x;
    const int wave = tid >> 6;
    const int lane = tid & 63;
    const int wr = wave >> 1, wc = wave & 1;     // 4x2 wave grid, 64x64 each

    // XCD-chunked swizzle: physical p -> logical L so XCD c gets L in [c*32, c*32+32)
    const int p = blockIdx.y * gridDim.x + blockIdx.x;   // 256 blocks
    const int L = (p & 7) * 32 + (p >> 3);
    const int bm = (L >> 4) * BM;
    const int bn = (L & 15) * BN;

    // --- staging addressing (round-2 swizzle: linear LDS dest, inverse-
    //     swizzled global source; chunk c at slot p = c ^ (row&7)) ---
    const int rsub = lane >> 3;
    const int cch = (lane & 7) ^ rsub;
    const unsigned short* srcA[4];
    const unsigned short* srcB[2];
#pragma unroll
    for (int i = 0; i < 4; i++) {
        const int row = (wave * 4 + i) * 8 + rsub;       // A: 32 groups of 8 rows
        srcA[i] = ((cch < 4) ? Ah : Al) + (size_t)(bm + row) * DIN + (cch & 3) * 8;
    }
#pragma unroll
    for (int i = 0; i < 2; i++) {
        const int row = (wave * 2 + i) * 8 + rsub;       // B: 16 groups
        srcB[i] = ((cch < 4) ? Wh : Wl) + (size_t)(bn + row) * DIN + (cch & 3) * 8;
    }

    // --- fragment read addressing (swizzled) ---
    const int fr = lane & 15;
    const int fq = lane >> 4;
    const int hiA_e = (wr * 64 + fr) * 64 + ((fq ^ (fr & 7)) * 8);
    const int hiB_e = (wc * 64 + fr) * 64 + ((fq ^ (fr & 7)) * 8);

    f32x4 acc[4][4];
#pragma unroll
    for (int i = 0; i < 4; i++)
#pragma unroll
        for (int j = 0; j < 4; j++) acc[i][j] = (f32x4){0.f, 0.f, 0.f, 0.f};

#define STAGE(buf, koff)                                                                   \
    do {                                                                                   \
        _Pragma("unroll")                                                                  \
        for (int i = 0; i < 4; i++)                                                        \
            __builtin_amdgcn_global_load_lds((gas_ptr)(srcA[i] + (koff)),                  \
                (las_ptr)(As + (buf) * 16384 + (wave * 4 + i) * 512), 16, 0, 0);           \
        _Pragma("unroll")                                                                  \
        for (int i = 0; i < 2; i++)                                                        \
            __builtin_amdgcn_global_load_lds((gas_ptr)(srcB[i] + (koff)),                  \
                (las_ptr)(Bs + (buf) * 8192 + (wave * 2 + i) * 512), 16, 0, 0);            \
    } while (0)

    STAGE(0, 0);
    __syncthreads();

    for (int kt = 0; kt < DIN / BK; ++kt) {
        const int cur = kt & 1;
        if (kt < DIN / BK - 1) STAGE(cur ^ 1, (kt + 1) * BK);

        const unsigned short* Ab = As + cur * 16384;
        const unsigned short* Bb = Bs + cur * 8192;
        bf16x8 ah[4], al[4], bh[4], bl[4];
#pragma unroll
        for (int mi = 0; mi < 4; mi++) {
            ah[mi] = *(const bf16x8*)(Ab + hiA_e + mi * 1024);
            al[mi] = *(const bf16x8*)(Ab + (hiA_e ^ 32) + mi * 1024);
        }
#pragma unroll
        for (int ni = 0; ni < 4; ni++) {
            bh[ni] = *(const bf16x8*)(Bb + hiB_e + ni * 1024);
            bl[ni] = *(const bf16x8*)(Bb + (hiB_e ^ 32) + ni * 1024);
        }
#pragma unroll
        for (int mi = 0; mi < 4; mi++)
#pragma unroll
            for (int ni = 0; ni < 4; ni++) {
                acc[mi][ni] = __builtin_amdgcn_mfma_f32_16x16x32_bf16(ah[mi], bh[ni], acc[mi][ni], 0, 0, 0);
                acc[mi][ni] = __builtin_amdgcn_mfma_f32_16x16x32_bf16(ah[mi], bl[ni], acc[mi][ni], 0, 0, 0);
                acc[mi][ni] = __builtin_amdgcn_mfma_f32_16x16x32_bf16(al[mi], bh[ni], acc[mi][ni], 0, 0, 0);
            }
        __syncthreads();
    }

    // --- epilogue: out = acc + Bres (bias & LoRA already in Bres) ---
#pragma unroll
    for (int mi = 0; mi < 4; mi++) {
#pragma unroll
        for (int j = 0; j < 4; j++) {
            const int n = bm + wr * 64 + mi * 16 + fq * 4 + j;
#pragma unroll
            for (int ni = 0; ni < 4; ni++) {
                const int o = bn + wc * 64 + ni * 16 + fr;
                out[(size_t)n * DOUT + o] = acc[mi][ni][j] + Bres[(size_t)n * DOUT + o];
            }
        }
    }
}

extern "C" void kernel_launch(void* const* d_in, const int* in_sizes, int n_in,
                              void* d_out, int out_size, void* d_ws, size_t ws_size,
                              hipStream_t stream) {
    const float* x    = (const float*)d_in[0];
    const int*   ids  = (const int*)d_in[1];
    const float* W    = (const float*)d_in[2];
    const float* bias = (const float*)d_in[3];
    const float* lA   = (const float*)d_in[4];
    const float* lB   = (const float*)d_in[5];
    const float* scal = (const float*)d_in[6];
    float* out = (float*)d_out;

    // workspace layout (~84.3 MB)
    unsigned short* x_hi = (unsigned short*)d_ws;
    unsigned short* x_lo = x_hi + (size_t)NTOK * DIN;
    unsigned short* w_hi = x_lo + (size_t)NTOK * DIN;
    unsigned short* w_lo = w_hi + (size_t)DOUT * DIN;
    float* Bres = (float*)(w_lo + (size_t)DOUT * DIN);
    float* ares = Bres + (size_t)NTOK * DOUT;
    int* list   = (int*)(ares + (size_t)NTOK * RANK);
    int* counts = list + (size_t)NLORA * NTOK;

    prep_kernel<<<dim3(6144 + NLORA), 256, 0, stream>>>(
        x, ids, W, x_hi, x_lo, w_hi, w_lo, list, counts);
    lora_a_grouped<<<dim3(NLORA, 8), 256, RANK * DIN * 4, stream>>>(
        x, lA, scal, list, counts, ares);
    lora_b_grouped<<<dim3(NLORA, 8), 256, RANK * BSTR * 4, stream>>>(
        lB, bias, ares, list, counts, Bres);
    gemm_lora_kernel<<<dim3(16, 16), 512, 96 * 1024, stream>>>(
        x_hi, x_lo, w_hi, w_lo, Bres, out);
}

// Round 4
// 177.686 us; speedup vs baseline: 1.7543x; 1.7543x over previous
//
#include <hip/hip_runtime.h>
#include <hip/hip_bf16.h>
#include <stdint.h>

#define NTOK 4096
#define DIN  2048
#define DOUT 2048
#define RANK 16
#define NLORA 32
#define LCAP 512   // max tokens per adapter handled (Binom(4096,1/32) tail: impossible)

typedef __attribute__((ext_vector_type(4))) float f32x4;
typedef __attribute__((ext_vector_type(8))) _Float16 f16x8;

typedef const __attribute__((address_space(1))) void* gas_ptr;
typedef __attribute__((address_space(3))) void* las_ptr;

// ---------------------------------------------------------------------------
// K1: convert W/x/lora_A/lora_B f32 -> fp16, build per-adapter token lists.
//   blocks [0,2048)     : W    (2048 elems/blk)
//   blocks [2048,6144)  : x
//   blocks [6144,6656)  : lora_A
//   blocks [6656,7168)  : lora_B
//   blocks [7168,7200)  : ballot token lists (one per adapter)
// ---------------------------------------------------------------------------
__global__ __launch_bounds__(256)
void prep_kernel(const float* __restrict__ x, const int* __restrict__ ids,
                 const float* __restrict__ W, const float* __restrict__ lA,
                 const float* __restrict__ lB,
                 _Float16* __restrict__ xh, _Float16* __restrict__ wh,
                 _Float16* __restrict__ lAh, _Float16* __restrict__ lBh,
                 int* __restrict__ list, int* __restrict__ counts) {
    const int bid = blockIdx.x;
    if (bid < 7168) {
        const float* src; _Float16* dst; int lb;
        if      (bid < 2048) { src = W;  dst = wh;  lb = bid; }
        else if (bid < 6144) { src = x;  dst = xh;  lb = bid - 2048; }
        else if (bid < 6656) { src = lA; dst = lAh; lb = bid - 6144; }
        else                 { src = lB; dst = lBh; lb = bid - 6656; }
        const size_t i = ((size_t)lb * 256 + threadIdx.x) * 8;
        f32x4 a = *(const f32x4*)(src + i);
        f32x4 b = *(const f32x4*)(src + i + 4);
        f16x8 h;
        h[0] = (_Float16)a.x; h[1] = (_Float16)a.y; h[2] = (_Float16)a.z; h[3] = (_Float16)a.w;
        h[4] = (_Float16)b.x; h[5] = (_Float16)b.y; h[6] = (_Float16)b.z; h[7] = (_Float16)b.w;
        *(f16x8*)(dst + i) = h;
        return;
    }
    // ---- token-list building for adapter a (validated in round 3) ----
    const int a = bid - 7168;
    const int wv = threadIdx.x >> 6;
    const int lane = threadIdx.x & 63;
    __shared__ int wcnt[4];
    int c = 0;
    for (int t0 = wv * 1024; t0 < wv * 1024 + 1024; t0 += 64)
        c += __popcll(__ballot(ids[t0 + lane] == a));
    if (lane == 0) wcnt[wv] = c;
    __syncthreads();
    int off = 0;
    for (int w = 0; w < wv; w++) off += wcnt[w];
    if (threadIdx.x == 0) counts[a] = wcnt[0] + wcnt[1] + wcnt[2] + wcnt[3];
    for (int t0 = wv * 1024; t0 < wv * 1024 + 1024; t0 += 64) {
        const int t = t0 + lane;
        const bool m = (ids[t] == a);
        unsigned long long bal = __ballot(m);
        if (m) {
            int pos = off + __popcll(bal & ((1ULL << lane) - 1));
            if (pos < LCAP) list[a * LCAP + pos] = t;
        }
        off += __popcll(bal);
    }
}

// ---------------------------------------------------------------------------
// K2: LoRA-A, gather-direct MFMA. Block (a, tile): 16 gathered tokens x 16
// ranks, K=2048 split across 8 waves (256 each); cross-wave LDS reduce.
// aresh[t][r] = scal[a] * dot(x[t], lora_A[a][r])  (fp16 out)
// ---------------------------------------------------------------------------
__global__ __launch_bounds__(512)
void lora_a_kernel(const _Float16* __restrict__ xh, const _Float16* __restrict__ lAh,
                   const float* __restrict__ scal, const int* __restrict__ list,
                   const int* __restrict__ counts, _Float16* __restrict__ aresh) {
    const int a = blockIdx.x, tile = blockIdx.y;
    const int cnt = counts[a];
    if (tile * 16 >= cnt) return;
    const int wave = threadIdx.x >> 6;
    const int lane = threadIdx.x & 63;
    const int fr = lane & 15, fq = lane >> 4;

    const int idxA = tile * 16 + fr;
    const int tA = (idxA < cnt) ? list[a * LCAP + idxA] : list[a * LCAP];

    const _Float16* xr = xh + (size_t)tA * DIN + wave * 256 + fq * 8;
    const _Float16* ar = lAh + (size_t)a * RANK * DIN + fr * DIN + wave * 256 + fq * 8;

    f32x4 acc = (f32x4){0.f, 0.f, 0.f, 0.f};
#pragma unroll
    for (int st = 0; st < 8; st++) {
        f16x8 af = *(const f16x8*)(xr + st * 32);
        f16x8 bf = *(const f16x8*)(ar + st * 32);
        acc = __builtin_amdgcn_mfma_f32_16x16x32_f16(af, bf, acc, 0, 0, 0);
    }

    __shared__ float red[8][256];
#pragma unroll
    for (int j = 0; j < 4; j++) red[wave][lane * 4 + j] = acc[j];
    __syncthreads();
    if (wave == 0) {
        const float s = scal[a];
#pragma unroll
        for (int j = 0; j < 4; j++) {
            float v = 0.f;
#pragma unroll
            for (int w = 0; w < 8; w++) v += red[w][lane * 4 + j];
            const int m = fq * 4 + j;                 // token within tile
            const int idx = tile * 16 + m;
            if (idx < cnt) {
                const int t = list[a * LCAP + idx];
                aresh[(size_t)t * RANK + fr] = (_Float16)(v * s);
            }
        }
    }
}

// ---------------------------------------------------------------------------
// K3: LoRA-B + bias -> Bres (fp16). Block (a, tile): 16 tokens x DOUT, K=16
// zero-padded to 32 (reuses the verified 16x16x32 layout). Wave w handles
// o-tiles w, w+8, ... (16 each).
// ---------------------------------------------------------------------------
__global__ __launch_bounds__(512)
void lora_b_kernel(const _Float16* __restrict__ aresh, const _Float16* __restrict__ lBh,
                   const float* __restrict__ bias, const int* __restrict__ list,
                   const int* __restrict__ counts, _Float16* __restrict__ Bresh) {
    const int a = blockIdx.x, tile = blockIdx.y;
    const int cnt = counts[a];
    if (tile * 16 >= cnt) return;
    const int wave = threadIdx.x >> 6;
    const int lane = threadIdx.x & 63;
    const int fr = lane & 15, fq = lane >> 4;

    // A-frag: ares rows (K=16 in low half, zeros in k16-31 lanes fq>=2)
    const int idxA = tile * 16 + fr;
    const int tA = (idxA < cnt) ? list[a * LCAP + idxA] : list[a * LCAP];
    f16x8 af = {};
    if (fq < 2) af = *(const f16x8*)(aresh + (size_t)tA * RANK + fq * 8);

    // token ids for the C rows this lane writes
    int tj[4];
#pragma unroll
    for (int j = 0; j < 4; j++) {
        const int idx = tile * 16 + fq * 4 + j;
        tj[j] = (idx < cnt) ? list[a * LCAP + idx] : -1;
    }

    const _Float16* Bb = lBh + (size_t)a * DOUT * RANK;
    for (int oi = 0; oi < 16; oi++) {
        const int ot = oi * 8 + wave;                // o-tile 0..127
        const int o = ot * 16 + fr;
        f16x8 bf = {};
        if (fq < 2) bf = *(const f16x8*)(Bb + (size_t)o * RANK + fq * 8);
        f32x4 c = (f32x4){0.f, 0.f, 0.f, 0.f};
        c = __builtin_amdgcn_mfma_f32_16x16x32_f16(af, bf, c, 0, 0, 0);
        const float bv = bias[o];
#pragma unroll
        for (int j = 0; j < 4; j++)
            if (tj[j] >= 0) Bresh[(size_t)tj[j] * DOUT + o] = (_Float16)(c[j] + bv);
    }
}

// ---------------------------------------------------------------------------
// K4: main GEMM, pure fp16 single-product. 256x128 tile, 8 waves (4x2),
// BK=32, dbuf LDS 48 KB, swizzled (slot = chunk ^ (row&3), 2-way max = free).
// XCD-chunked block swizzle. Epilogue: out = acc + Bresh.
// ---------------------------------------------------------------------------
#define BM 256
#define BN 128
#define BK 32

__global__ __launch_bounds__(512, 2)
void gemm_kernel(const _Float16* __restrict__ Ah, const _Float16* __restrict__ Wh,
                 const _Float16* __restrict__ Bresh, float* __restrict__ out) {
    extern __shared__ _Float16 sm[];
    _Float16* As = sm;            // 2 x 8192 halfs (16 KB each)
    _Float16* Bs = sm + 16384;    // 2 x 4096 halfs (8 KB each)

    const int tid = threadIdx.x;
    const int wave = tid >> 6;
    const int lane = tid & 63;
    const int wr = wave >> 1, wc = wave & 1;         // 4x2 waves of 64x64

    const int p = blockIdx.y * gridDim.x + blockIdx.x;   // 256 blocks
    const int L = (p & 7) * 32 + (p >> 3);               // XCD-chunked
    const int bm = (L >> 4) * BM;
    const int bn = (L & 15) * BN;

    // staging: inst g covers rows [g*16,g*16+16); lane -> row g*16+(lane>>2),
    // slot lane&3 holds source chunk c = (lane&3) ^ (row&3)
    const int rsub = lane >> 2;                      // row&15... row&3 = rsub&3
    const int cch = (lane & 3) ^ (rsub & 3);
    const _Float16* srcA[2];
    const _Float16* srcB;
    {
        const int rowA0 = (wave * 2 + 0) * 16 + rsub;
        const int rowA1 = (wave * 2 + 1) * 16 + rsub;
        srcA[0] = Ah + (size_t)(bm + rowA0) * DIN + cch * 8;
        srcA[1] = Ah + (size_t)(bm + rowA1) * DIN + cch * 8;
        const int rowB = wave * 16 + rsub;
        srcB = Wh + (size_t)(bn + rowB) * DIN + cch * 8;
    }

    const int fr = lane & 15;
    const int fq = lane >> 4;
    const int aoff = (wr * 64 + fr) * 32 + ((fq ^ (fr & 3)) * 8);
    const int boff = (wc * 64 + fr) * 32 + ((fq ^ (fr & 3)) * 8);

    f32x4 acc[4][4];
#pragma unroll
    for (int i = 0; i < 4; i++)
#pragma unroll
        for (int j = 0; j < 4; j++) acc[i][j] = (f32x4){0.f, 0.f, 0.f, 0.f};

#define STAGE(buf, koff)                                                                  \
    do {                                                                                  \
        __builtin_amdgcn_global_load_lds((gas_ptr)(srcA[0] + (koff)),                     \
            (las_ptr)(As + (buf) * 8192 + (wave * 2 + 0) * 512), 16, 0, 0);               \
        __builtin_amdgcn_global_load_lds((gas_ptr)(srcA[1] + (koff)),                     \
            (las_ptr)(As + (buf) * 8192 + (wave * 2 + 1) * 512), 16, 0, 0);               \
        __builtin_amdgcn_global_load_lds((gas_ptr)(srcB + (koff)),                        \
            (las_ptr)(Bs + (buf) * 4096 + wave * 512), 16, 0, 0);                         \
    } while (0)

    STAGE(0, 0);
    __syncthreads();

    for (int kt = 0; kt < DIN / BK; ++kt) {
        const int cur = kt & 1;
        if (kt < DIN / BK - 1) STAGE(cur ^ 1, (kt + 1) * BK);

        const _Float16* Ab = As + cur * 8192;
        const _Float16* Bb = Bs + cur * 4096;
        f16x8 ah[4], bh[4];
#pragma unroll
        for (int mi = 0; mi < 4; mi++) ah[mi] = *(const f16x8*)(Ab + aoff + mi * 512);
#pragma unroll
        for (int ni = 0; ni < 4; ni++) bh[ni] = *(const f16x8*)(Bb + boff + ni * 512);
#pragma unroll
        for (int mi = 0; mi < 4; mi++)
#pragma unroll
            for (int ni = 0; ni < 4; ni++)
                acc[mi][ni] = __builtin_amdgcn_mfma_f32_16x16x32_f16(ah[mi], bh[ni], acc[mi][ni], 0, 0, 0);
        __syncthreads();
    }

    // epilogue: out = acc + Bresh (bias + scaled LoRA already inside)
#pragma unroll
    for (int mi = 0; mi < 4; mi++) {
#pragma unroll
        for (int j = 0; j < 4; j++) {
            const int n = bm + wr * 64 + mi * 16 + fq * 4 + j;
#pragma unroll
            for (int ni = 0; ni < 4; ni++) {
                const int o = bn + wc * 64 + ni * 16 + fr;
                out[(size_t)n * DOUT + o] = acc[mi][ni][j] + (float)Bresh[(size_t)n * DOUT + o];
            }
        }
    }
}

extern "C" void kernel_launch(void* const* d_in, const int* in_sizes, int n_in,
                              void* d_out, int out_size, void* d_ws, size_t ws_size,
                              hipStream_t stream) {
    const float* x    = (const float*)d_in[0];
    const int*   ids  = (const int*)d_in[1];
    const float* W    = (const float*)d_in[2];
    const float* bias = (const float*)d_in[3];
    const float* lA   = (const float*)d_in[4];
    const float* lB   = (const float*)d_in[5];
    const float* scal = (const float*)d_in[6];
    float* out = (float*)d_out;

    // workspace layout (~47 MB)
    _Float16* xh    = (_Float16*)d_ws;                       // 8,388,608
    _Float16* wh    = xh + (size_t)NTOK * DIN;               // 4,194,304
    _Float16* lAh   = wh + (size_t)DOUT * DIN;               // 1,048,576
    _Float16* lBh   = lAh + (size_t)NLORA * RANK * DIN;      // 1,048,576
    _Float16* aresh = lBh + (size_t)NLORA * DOUT * RANK;     //    65,536
    _Float16* Bresh = aresh + (size_t)NTOK * RANK;           // 8,388,608
    int* list   = (int*)(Bresh + (size_t)NTOK * DOUT);
    int* counts = list + (size_t)NLORA * LCAP;

    prep_kernel<<<dim3(7168 + NLORA), 256, 0, stream>>>(
        x, ids, W, lA, lB, xh, wh, lAh, lBh, list, counts);
    lora_a_kernel<<<dim3(NLORA, 32), 512, 0, stream>>>(
        xh, lAh, scal, list, counts, aresh);
    lora_b_kernel<<<dim3(NLORA, 32), 512, 0, stream>>>(
        aresh, lBh, bias, list, counts, Bresh);
    gemm_kernel<<<dim3(16, 16), 512, 48 * 1024, stream>>>(
        xh, wh, Bresh, out);
}

// Round 5
// 162.740 us; speedup vs baseline: 1.9154x; 1.0918x over previous
//
#include <hip/hip_runtime.h>
#include <hip/hip_bf16.h>
#include <stdint.h>

#define NTOK 4096
#define DIN  2048
#define DOUT 2048
#define RANK 16
#define NLORA 32
#define LCAP 512

typedef __attribute__((ext_vector_type(4))) float f32x4;
typedef __attribute__((ext_vector_type(8))) _Float16 f16x8;

typedef const __attribute__((address_space(1))) void* gas_ptr;
typedef __attribute__((address_space(3))) void* las_ptr;

// ---------------------------------------------------------------------------
// K1: convert W/x/lora_A/lora_B f32 -> fp16 + per-adapter token lists.
// ---------------------------------------------------------------------------
__global__ __launch_bounds__(256)
void prep_kernel(const float* __restrict__ x, const int* __restrict__ ids,
                 const float* __restrict__ W, const float* __restrict__ lA,
                 const float* __restrict__ lB,
                 _Float16* __restrict__ xh, _Float16* __restrict__ wh,
                 _Float16* __restrict__ lAh, _Float16* __restrict__ lBh,
                 int* __restrict__ list, int* __restrict__ counts) {
    const int bid = blockIdx.x;
    if (bid < 7168) {
        const float* src; _Float16* dst; int lb;
        if      (bid < 2048) { src = W;  dst = wh;  lb = bid; }
        else if (bid < 6144) { src = x;  dst = xh;  lb = bid - 2048; }
        else if (bid < 6656) { src = lA; dst = lAh; lb = bid - 6144; }
        else                 { src = lB; dst = lBh; lb = bid - 6656; }
        const size_t i = ((size_t)lb * 256 + threadIdx.x) * 8;
        f32x4 a = *(const f32x4*)(src + i);
        f32x4 b = *(const f32x4*)(src + i + 4);
        f16x8 h;
        h[0] = (_Float16)a.x; h[1] = (_Float16)a.y; h[2] = (_Float16)a.z; h[3] = (_Float16)a.w;
        h[4] = (_Float16)b.x; h[5] = (_Float16)b.y; h[6] = (_Float16)b.z; h[7] = (_Float16)b.w;
        *(f16x8*)(dst + i) = h;
        return;
    }
    const int a = bid - 7168;
    const int wv = threadIdx.x >> 6;
    const int lane = threadIdx.x & 63;
    __shared__ int wcnt[4];
    int c = 0;
    for (int t0 = wv * 1024; t0 < wv * 1024 + 1024; t0 += 64)
        c += __popcll(__ballot(ids[t0 + lane] == a));
    if (lane == 0) wcnt[wv] = c;
    __syncthreads();
    int off = 0;
    for (int w = 0; w < wv; w++) off += wcnt[w];
    if (threadIdx.x == 0) counts[a] = wcnt[0] + wcnt[1] + wcnt[2] + wcnt[3];
    for (int t0 = wv * 1024; t0 < wv * 1024 + 1024; t0 += 64) {
        const int t = t0 + lane;
        const bool m = (ids[t] == a);
        unsigned long long bal = __ballot(m);
        if (m) {
            int pos = off + __popcll(bal & ((1ULL << lane) - 1));
            if (pos < LCAP) list[a * LCAP + pos] = t;
        }
        off += __popcll(bal);
    }
}

// ---------------------------------------------------------------------------
// K2: fused LoRA A+B. Block (a, tile): 16 gathered tokens.
//   stage 1: ares[16 tok][16 r] = scal * x @ lora_A^T   (8-wave K-split MFMA,
//            cross-wave LDS reduce, result kept in LDS as fp16)
//   stage 2: Bresh[t][o] = bias[o] + sum_r ares[t][r]*lora_B[o][r]
//            (wave w owns o-tiles [w*16, w*16+16), K=16 zero-padded MFMA)
// Fragment roles identical to round-4's validated K2/K3 kernels.
// ---------------------------------------------------------------------------
__global__ __launch_bounds__(512)
void lora_fused_kernel(const _Float16* __restrict__ xh, const _Float16* __restrict__ lAh,
                       const _Float16* __restrict__ lBh, const float* __restrict__ bias,
                       const float* __restrict__ scal, const int* __restrict__ list,
                       const int* __restrict__ counts, _Float16* __restrict__ Bresh) {
    const int a = blockIdx.x, tile = blockIdx.y;
    const int cnt = counts[a];
    if (tile * 16 >= cnt) return;
    const int wave = threadIdx.x >> 6;
    const int lane = threadIdx.x & 63;
    const int fr = lane & 15, fq = lane >> 4;

    __shared__ float red[8][256];
    __shared__ _Float16 ares_h[16 * 16];

    const int idxA = tile * 16 + fr;
    const int tA = (idxA < cnt) ? list[a * LCAP + idxA] : list[a * LCAP];

    // ---- stage 1: A-projection ----
    const _Float16* xr = xh + (size_t)tA * DIN + wave * 256 + fq * 8;
    const _Float16* ar = lAh + (size_t)a * RANK * DIN + fr * DIN + wave * 256 + fq * 8;
    f32x4 acc = (f32x4){0.f, 0.f, 0.f, 0.f};
#pragma unroll
    for (int st = 0; st < 8; st++) {
        f16x8 af = *(const f16x8*)(xr + st * 32);
        f16x8 bf = *(const f16x8*)(ar + st * 32);
        acc = __builtin_amdgcn_mfma_f32_16x16x32_f16(af, bf, acc, 0, 0, 0);
    }
#pragma unroll
    for (int j = 0; j < 4; j++) red[wave][lane * 4 + j] = acc[j];
    __syncthreads();
    if (wave == 0) {
        const float s = scal[a];
#pragma unroll
        for (int j = 0; j < 4; j++) {
            float v = 0.f;
#pragma unroll
            for (int w = 0; w < 8; w++) v += red[w][lane * 4 + j];
            ares_h[(fq * 4 + j) * RANK + fr] = (_Float16)(v * s);   // [token][rank]
        }
    }
    __syncthreads();

    // ---- stage 2: B-expansion + bias ----
    f16x8 af = {};
    if (fq < 2) af = *(const f16x8*)(ares_h + fr * RANK + fq * 8);
    int tj[4];
#pragma unroll
    for (int j = 0; j < 4; j++) {
        const int idx = tile * 16 + fq * 4 + j;
        tj[j] = (idx < cnt) ? list[a * LCAP + idx] : -1;
    }
    const _Float16* Bb = lBh + (size_t)a * DOUT * RANK;
#pragma unroll 4
    for (int oi = 0; oi < 16; oi++) {
        const int o = (wave * 16 + oi) * 16 + fr;
        f16x8 bf = {};
        if (fq < 2) bf = *(const f16x8*)(Bb + (size_t)o * RANK + fq * 8);
        f32x4 c = (f32x4){0.f, 0.f, 0.f, 0.f};
        c = __builtin_amdgcn_mfma_f32_16x16x32_f16(af, bf, c, 0, 0, 0);
        const float bv = bias[o];
#pragma unroll
        for (int j = 0; j < 4; j++)
            if (tj[j] >= 0) Bresh[(size_t)tj[j] * DOUT + o] = (_Float16)(c[j] + bv);
    }
}

// ---------------------------------------------------------------------------
// K3: main GEMM fp16. 128x128 tile, 4 waves (2x2 of 64x64), BK=64.
// LDS 64 KB dbuf -> 2 blocks/CU. Proven 8-slot swizzle (slot = chunk^(row&7),
// rounds 2-3: conflicts == 0). Counted-vmcnt pipeline (T4): vmcnt(8) before
// barrier1 -> this wave's tile-k loads landed; all waves at barrier1 -> whole
// tile landed. barrier2 after MFMA protects cur from next STAGE overwrite
// (ds_reads complete before MFMA via compiler lgkmcnt). Never drains to 0
// in-loop. T5 setprio around MFMA cluster. XCD-chunked block swizzle.
// ---------------------------------------------------------------------------
#define GBK 64
#define NT (DIN / GBK)

__global__ __launch_bounds__(256, 2)
void gemm_kernel(const _Float16* __restrict__ Ah, const _Float16* __restrict__ Wh,
                 const _Float16* __restrict__ Bresh, float* __restrict__ out) {
    extern __shared__ _Float16 sm[];
    _Float16* As = sm;             // 2 x 8192 halfs
    _Float16* Bs = sm + 16384;     // 2 x 8192 halfs

    const int tid = threadIdx.x;
    const int wave = tid >> 6;
    const int lane = tid & 63;
    const int wr = wave >> 1, wc = wave & 1;          // 2x2 waves of 64x64

    // XCD-chunked swizzle: 512 blocks, XCD c owns logical [c*64, c*64+64)
    // = 4 M-panels x all 16 N-panels (A-panels L2-resident per XCD).
    const int p = blockIdx.x;
    const int L = (p & 7) * 64 + (p >> 3);
    const int bm = (L >> 4) * 128;
    const int bn = (L & 15) * 128;

    // staging: wave w inst i covers rows [(w*4+i)*8, +8); lane -> row +(lane>>3),
    // slot lane&7 holds source chunk c = (lane&7) ^ (lane>>3)  [8 chunks/row]
    const int rsub = lane >> 3;
    const int cch = (lane & 7) ^ rsub;
    const _Float16* srcA[4];
    const _Float16* srcB[4];
#pragma unroll
    for (int i = 0; i < 4; i++) {
        const int row = (wave * 4 + i) * 8 + rsub;
        srcA[i] = Ah + (size_t)(bm + row) * DIN + cch * 8;
        srcB[i] = Wh + (size_t)(bn + row) * DIN + cch * 8;
    }

    const int fr = lane & 15;
    const int fq = lane >> 4;

    f32x4 acc[4][4];
#pragma unroll
    for (int i = 0; i < 4; i++)
#pragma unroll
        for (int j = 0; j < 4; j++) acc[i][j] = (f32x4){0.f, 0.f, 0.f, 0.f};

#define STAGE(buf, koff)                                                                  \
    do {                                                                                  \
        _Pragma("unroll")                                                                 \
        for (int i = 0; i < 4; i++) {                                                     \
            __builtin_amdgcn_global_load_lds((gas_ptr)(srcA[i] + (koff)),                 \
                (las_ptr)(As + (buf) * 8192 + (wave * 4 + i) * 512), 16, 0, 0);           \
            __builtin_amdgcn_global_load_lds((gas_ptr)(srcB[i] + (koff)),                 \
                (las_ptr)(Bs + (buf) * 8192 + (wave * 4 + i) * 512), 16, 0, 0);           \
        }                                                                                 \
    } while (0)

    STAGE(0, 0);

    for (int kt = 0; kt < NT; ++kt) {
        const int cur = kt & 1;
        if (kt < NT - 1) {
            STAGE(cur ^ 1, (kt + 1) * GBK);
            asm volatile("s_waitcnt vmcnt(8)" ::: "memory");
        } else {
            asm volatile("s_waitcnt vmcnt(0)" ::: "memory");
        }
        __builtin_amdgcn_s_barrier();
        __builtin_amdgcn_sched_barrier(0);

        const _Float16* Ab = As + cur * 8192;
        const _Float16* Bb = Bs + cur * 8192;
#pragma unroll
        for (int kk = 0; kk < 2; kk++) {
            f16x8 av[4], bv[4];
#pragma unroll
            for (int mi = 0; mi < 4; mi++) {
                const int row = wr * 64 + mi * 16 + fr;
                const int slot = (kk * 4 + fq) ^ (row & 7);
                av[mi] = *(const f16x8*)(Ab + row * 64 + slot * 8);
            }
#pragma unroll
            for (int ni = 0; ni < 4; ni++) {
                const int row = wc * 64 + ni * 16 + fr;
                const int slot = (kk * 4 + fq) ^ (row & 7);
                bv[ni] = *(const f16x8*)(Bb + row * 64 + slot * 8);
            }
            __builtin_amdgcn_s_setprio(1);
#pragma unroll
            for (int mi = 0; mi < 4; mi++)
#pragma unroll
                for (int ni = 0; ni < 4; ni++)
                    acc[mi][ni] = __builtin_amdgcn_mfma_f32_16x16x32_f16(av[mi], bv[ni], acc[mi][ni], 0, 0, 0);
            __builtin_amdgcn_s_setprio(0);
        }
        __builtin_amdgcn_s_barrier();
    }

    // epilogue: out = acc + Bresh (bias + scaled LoRA inside Bresh)
#pragma unroll
    for (int mi = 0; mi < 4; mi++) {
#pragma unroll
        for (int j = 0; j < 4; j++) {
            const int n = bm + wr * 64 + mi * 16 + fq * 4 + j;
#pragma unroll
            for (int ni = 0; ni < 4; ni++) {
                const int o = bn + wc * 64 + ni * 16 + fr;
                out[(size_t)n * DOUT + o] = acc[mi][ni][j] + (float)Bresh[(size_t)n * DOUT + o];
            }
        }
    }
}

extern "C" void kernel_launch(void* const* d_in, const int* in_sizes, int n_in,
                              void* d_out, int out_size, void* d_ws, size_t ws_size,
                              hipStream_t stream) {
    const float* x    = (const float*)d_in[0];
    const int*   ids  = (const int*)d_in[1];
    const float* W    = (const float*)d_in[2];
    const float* bias = (const float*)d_in[3];
    const float* lA   = (const float*)d_in[4];
    const float* lB   = (const float*)d_in[5];
    const float* scal = (const float*)d_in[6];
    float* out = (float*)d_out;

    _Float16* xh    = (_Float16*)d_ws;                       // 16 MB
    _Float16* wh    = xh + (size_t)NTOK * DIN;               // 8 MB
    _Float16* lAh   = wh + (size_t)DOUT * DIN;               // 2 MB
    _Float16* lBh   = lAh + (size_t)NLORA * RANK * DIN;      // 2 MB
    _Float16* Bresh = lBh + (size_t)NLORA * DOUT * RANK;     // 16 MB
    int* list   = (int*)(Bresh + (size_t)NTOK * DOUT);
    int* counts = list + (size_t)NLORA * LCAP;

    prep_kernel<<<dim3(7168 + NLORA), 256, 0, stream>>>(
        x, ids, W, lA, lB, xh, wh, lAh, lBh, list, counts);
    lora_fused_kernel<<<dim3(NLORA, 32), 512, 0, stream>>>(
        xh, lAh, lBh, bias, scal, list, counts, Bresh);
    gemm_kernel<<<dim3(512), 256, 64 * 1024, stream>>>(
        xh, wh, Bresh, out);
}